// Round 3
// baseline (177.417 us; speedup 1.0000x reference)
//
#include <hip/hip_runtime.h>

#define N_ROWS 8192
#define DIMS   256
#define NTILE  64                      // 8192 / 128
#define NBLK   2080                    // NTILE*(NTILE+1)/2 triangle tiles
#define K1B    64                      // k1 blocks (128 rows each)

typedef _Float16 f16x4 __attribute__((ext_vector_type(4)));
typedef _Float16 f16x8 __attribute__((ext_vector_type(8)));
typedef float   f32x16 __attribute__((ext_vector_type(16)));

// ws layout:
// [0, 4MB)        : fp16 plane of x, MFMA-fragment-permuted:
//                   [rowblk=row/32][ks=k/16][slot=(row%32)+32*((k%16)/8)][(k%8)]
// [4MB, +32KB)    : float sq[8192]
// then            : colpart[64][256], ssqpart[64], n0part[64], Scalars
#define WS_PLANE  0
#define WS_SQ     (4 * 1024 * 1024)
#define WS_COLP   (WS_SQ + 32768)
#define WS_SSQ    (WS_COLP + K1B * 256 * 4)
#define WS_N0     (WS_SSQ + K1B * 4)
#define WS_SC     (WS_N0 + K1B * 4)

struct Scalars {
    double result;        // accumulated by k3 blocks (atomic f64)
    unsigned int ticket;  // completion counter
    float c2;             // -log2(e) / (16*bw)
    float w0;             // +1/n0
    float w1;             // -1/n1
};

// ---------------------------------------------------------------- K1: stats + fp16 plane (no atomics)
// 64 blocks x 256 threads; block owns 128 rows, each wave 32 rows.
__global__ __launch_bounds__(256) void k1_rows(const float* __restrict__ x,
                                               const long long* __restrict__ sub,
                                               float* __restrict__ sq,
                                               float* __restrict__ colpart,
                                               float* __restrict__ ssqpart,
                                               unsigned int* __restrict__ n0part,
                                               unsigned short* __restrict__ plane) {
    __shared__ float cls[4][256];
    __shared__ float smq[4];
    const int t = threadIdx.x;
    const int l = t & 63;
    const int w = t >> 6;
    const int base = blockIdx.x * 128;

    float4 colacc = make_float4(0.f, 0.f, 0.f, 0.f);
    float  my_sumsq = 0.f;

    // plane dest components that only depend on lane
    const int ks  = l >> 2;
    const int s16 = l & 3;
    const int lslot_add = ((s16 >> 1) << 5);
    const int lhalf_add = (s16 & 1) * 4;

    for (int r = 0; r < 32; ++r) {
        const int row = base + w * 32 + r;
        const float4 v = ((const float4*)(x + (size_t)row * DIMS))[l];
        colacc.x += v.x; colacc.y += v.y; colacc.z += v.z; colacc.w += v.w;

        const size_t hidx = ((size_t)(row >> 5) * 16 + ks) * 512
                          + (size_t)(((row & 31) + lslot_add) * 8 + lhalf_add);
        f16x4 h = { (_Float16)v.x, (_Float16)v.y, (_Float16)v.z, (_Float16)v.w };
        *(f16x4*)(plane + hidx) = h;

        float s = v.x * v.x + v.y * v.y + v.z * v.z + v.w * v.w;
        #pragma unroll
        for (int off = 32; off; off >>= 1) s += __shfl_down(s, off, 64);
        if (l == 0) { sq[row] = s; my_sumsq += s; }
    }
    if (l == 0) smq[w] = my_sumsq;
    *(float4*)&cls[w][l * 4] = colacc;
    __syncthreads();

    colpart[blockIdx.x * 256 + t] = cls[0][t] + cls[1][t] + cls[2][t] + cls[3][t];
    if (t == 0) ssqpart[blockIdx.x] = smq[0] + smq[1] + smq[2] + smq[3];
    if (w == 0) {
        unsigned long long m1 = __ballot((int)sub[base + l] == 0);
        unsigned long long m2 = __ballot((int)sub[base + 64 + l] == 0);
        if (l == 0) n0part[blockIdx.x] = (unsigned int)(__popcll(m1) + __popcll(m2));
    }
}

// ---------------------------------------------------------------- K2: reduce partials -> scalars; init accumulators
__global__ __launch_bounds__(256) void k2_scalars(const float* __restrict__ colpart,
                                                  const float* __restrict__ ssqpart,
                                                  const unsigned int* __restrict__ n0part,
                                                  Scalars* sc) {
    __shared__ float a1[256], a2[256];
    __shared__ unsigned int a3[256];
    const int t = threadIdx.x;

    float cs = 0.f;
    #pragma unroll 8
    for (int b = 0; b < K1B; ++b) cs += colpart[b * 256 + t];   // coalesced
    a1[t] = cs * cs;
    a2[t] = (t < K1B) ? ssqpart[t] : 0.f;
    a3[t] = (t < K1B) ? n0part[t] : 0u;
    __syncthreads();
    for (int s = 128; s; s >>= 1) {
        if (t < s) { a1[t] += a1[t + s]; a2[t] += a2[t + s]; a3[t] += a3[t + s]; }
        __syncthreads();
    }
    if (t == 0) {
        const double n = (double)N_ROWS;
        // sum(L2) = 2n*sum(sq) - 2*||colsum||^2  (diag clamp negligible)
        const double sumL2 = 2.0 * n * (double)a2[0] - 2.0 * (double)a1[0];
        const double bw = sumL2 / (n * n - n) / 4.0;   // / KERNEL_MUL^(KERNEL_NUM/2)
        sc->c2 = (float)(-1.4426950408889634 / (16.0 * bw));
        const double n0 = (double)a3[0];
        const double n1 = n - n0;
        sc->w0 = (float)( 1.0 / n0);
        sc->w1 = (float)(-1.0 / n1);
        sc->result = 0.0;
        sc->ticket = 0u;
    }
}

// ---------------------------------------------------------------- K3: fp16 MFMA Gram + kernel + reduce
// 1D triangle grid (2080 blocks). Block tile 128x128, 4 waves (2x2),
// wave tile 64x64 = 2x2 frags of 32x32x16_f16, BK=32, double-buffered 2x16KB LDS,
// staged via global_load_lds from the pre-permuted fp16 plane.
__global__ __launch_bounds__(256, 3) void k3_mmd(const unsigned short* __restrict__ plane,
                                                 const long long* __restrict__ sub,
                                                 const float* __restrict__ sq,
                                                 Scalars* sc,
                                                 float* __restrict__ out) {
    __shared__ char lds[32768];     // 2 x (A 8KB + B 8KB)
    __shared__ float2 sqwI[128], sqwJ[128];
    __shared__ float red4[4];

    // decode upper-triangle tile (bi <= bj), row-major enumeration
    int bi = 0, rem = blockIdx.x;
    while (rem >= NTILE - bi) { rem -= NTILE - bi; ++bi; }
    const int bj = bi + rem;
    const bool diag = (bi == bj);

    const int t  = threadIdx.x;
    const int l  = t & 63;
    const int w  = t >> 6;
    const int wr = w >> 1;
    const int wc = w & 1;

    const float c2 = sc->c2, w0 = sc->w0, w1 = sc->w1;

    // stage one BK=32 chunk (ks pair kbase,kbase+1): 16 regions x 1KB, 4 per wave
    auto stage = [&](int kbase, int bufb) {
        #pragma unroll
        for (int i = 0; i < 4; ++i) {
            const int id = w * 4 + i;
            size_t grb;
            if (id < 8) {
                grb = (size_t)((bi * 4 + (id >> 1)) * 16 + kbase + (id & 1));
            } else {
                const int ib = id - 8;
                grb = (size_t)((bj * 4 + (ib >> 1)) * 16 + kbase + (ib & 1));
            }
            const unsigned short* g = plane + grb * 512 + l * 8;   // 16B/lane
            char* lp = lds + bufb + id * 1024;                     // wave-uniform dest
            __builtin_amdgcn_global_load_lds(
                (const __attribute__((address_space(1))) unsigned int*)(const void*)g,
                (__attribute__((address_space(3))) unsigned int*)(void*)lp, 16, 0, 0);
        }
    };

    f32x16 acc[2][2] = {};
    auto compute = [&](int bufb) {
        #pragma unroll
        for (int ksL = 0; ksL < 2; ++ksL) {
            f16x8 a[2], b[2];
            #pragma unroll
            for (int m = 0; m < 2; ++m)
                a[m] = *(const f16x8*)(lds + bufb + ((wr * 2 + m) * 2 + ksL) * 1024 + l * 16);
            #pragma unroll
            for (int n = 0; n < 2; ++n)
                b[n] = *(const f16x8*)(lds + bufb + 8192 + ((wc * 2 + n) * 2 + ksL) * 1024 + l * 16);
            #pragma unroll
            for (int m = 0; m < 2; ++m)
                #pragma unroll
                for (int n = 0; n < 2; ++n)
                    acc[m][n] = __builtin_amdgcn_mfma_f32_32x32x16_f16(a[m], b[n], acc[m][n], 0, 0, 0);
        }
    };

    stage(0, 0);
    // cooperative stage of per-row (sq, weight) — kills scattered epilogue loads.
    // fold f=2 (off-diagonal double count) into the I-side weight.
    {
        const int idx = t & 127;
        const float fold = diag ? 1.f : 2.f;
        if (t < 128) {
            const int I = bi * 128 + idx;
            const float wv = ((int)sub[I] == 0) ? w0 : w1;
            sqwI[idx] = make_float2(sq[I], wv * fold);
        } else {
            const int J = bj * 128 + idx;
            const float wv = ((int)sub[J] == 0) ? w0 : w1;
            sqwJ[idx] = make_float2(sq[J], wv);
        }
    }
    __syncthreads();

    for (int c = 0; c < 8; ++c) {
        if (c < 7) stage((c + 1) * 2, ((c + 1) & 1) * 16384);  // prefetch under compute
        compute((c & 1) * 16384);
        __syncthreads();
    }

    // ---------------- epilogue: L2 -> multi-scale kernel -> weighted partial sum
    const int lh = l >> 5;
    const int ln = l & 31;
    float sJ[2], wJ[2];
    #pragma unroll
    for (int n = 0; n < 2; ++n) {
        const float2 p = sqwJ[wc * 64 + n * 32 + ln];
        sJ[n] = p.x; wJ[n] = p.y;
    }

    float part = 0.f;
    #pragma unroll
    for (int m = 0; m < 2; ++m) {
        #pragma unroll
        for (int r = 0; r < 16; ++r) {
            // C/D layout: col = lane&31, row = (r&3) + 8*(r>>2) + 4*(lane>>5)
            const int Il = wr * 64 + m * 32 + (r & 3) + ((r >> 2) << 3) + (lh << 2);
            const float2 pi = sqwI[Il];
            #pragma unroll
            for (int n = 0; n < 2; ++n) {
                const float g = acc[m][n][r];
                float l2 = fmaxf(pi.x + sJ[n] - 2.f * g, 0.f);
                const float tt  = __builtin_amdgcn_exp2f(l2 * c2);  // exp(-L2/(16*bw))
                const float t2  = tt * tt;
                const float t4  = t2 * t2;
                const float t8  = t4 * t4;
                const float t16 = t8 * t8;
                const float K   = ((tt + t2) + (t4 + t8)) + t16;
                float w2 = pi.y * wJ[n];
                if (diag) {
                    const int Jl = wc * 64 + n * 32 + ln;
                    const float f = (Il < Jl) ? 2.f : ((Il == Jl) ? 1.f : 0.f);
                    w2 *= f;
                }
                part = fmaf(K, w2, part);
            }
        }
    }

    // wave shuffle-reduce, then 4 values via LDS (1 barrier)
    #pragma unroll
    for (int off = 32; off; off >>= 1) part += __shfl_down(part, off, 64);
    if (l == 0) red4[w] = part;
    __syncthreads();
    if (t == 0) {
        atomicAdd(&sc->result, (double)(red4[0] + red4[1] + red4[2] + red4[3]));
        __threadfence();
        const unsigned int old = atomicAdd(&sc->ticket, 1u);
        if (old == NBLK - 1) out[0] = (float)atomicAdd(&sc->result, 0.0);  // last block emits
    }
}

extern "C" void kernel_launch(void* const* d_in, const int* in_sizes, int n_in,
                              void* d_out, int out_size, void* d_ws, size_t ws_size,
                              hipStream_t stream) {
    const long long* sub = (const long long*)d_in[0];   // subggroup int64 (N,1)
    const float*     x   = (const float*)d_in[1];       // outputs fp32 (N,256)
    float* out = (float*)d_out;

    char* ws = (char*)d_ws;
    unsigned short* plane   = (unsigned short*)(ws + WS_PLANE);
    float*          sq      = (float*)(ws + WS_SQ);
    float*          colpart = (float*)(ws + WS_COLP);
    float*          ssqpart = (float*)(ws + WS_SSQ);
    unsigned int*   n0part  = (unsigned int*)(ws + WS_N0);
    Scalars*        sc      = (Scalars*)(ws + WS_SC);

    k1_rows<<<K1B, 256, 0, stream>>>(x, sub, sq, colpart, ssqpart, n0part, plane);
    k2_scalars<<<1, 256, 0, stream>>>(colpart, ssqpart, n0part, sc);
    k3_mmd<<<NBLK, 256, 0, stream>>>(plane, sub, sq, sc, out);
}

// Round 5
// 163.447 us; speedup vs baseline: 1.0855x; 1.0855x over previous
//
#include <hip/hip_runtime.h>

#define N_ROWS 8192
#define DIMS   256
#define NTILE  64                      // 8192 / 128
#define NBLK   2080                    // NTILE*(NTILE+1)/2 triangle tiles (= 8*260)
#define K1B    512                     // k1 blocks (16 rows each)

typedef _Float16 f16x4 __attribute__((ext_vector_type(4)));
typedef _Float16 f16x8 __attribute__((ext_vector_type(8)));
typedef float   f32x16 __attribute__((ext_vector_type(16)));

// ws layout:
// [0, 4MB)        : fp16 plane of x, MFMA-fragment-permuted:
//                   [rowblk=row/32][ks=k/16][slot=(row%32)+32*((k%16)/8)][(k%8)]
// [4MB, +32KB)    : float sq[8192]
// then            : colpart[K1B][256], ssqpart[K1B], n0part[K1B], Scalars
#define WS_PLANE  0
#define WS_SQ     (4 * 1024 * 1024)
#define WS_COLP   (WS_SQ + 32768)
#define WS_SSQ    (WS_COLP + K1B * 256 * 4)
#define WS_N0     (WS_SSQ + K1B * 4)
#define WS_SC     (WS_N0 + K1B * 4)

struct Scalars {
    double result;        // accumulated by k3 blocks (atomic f64)
    unsigned int ticket;  // completion counter
    float c2;             // -log2(e) / (16*bw)
    float w0;             // +1/n0
    float w1;             // -1/n1
};

// ---------------------------------------------------------------- K1: stats + fp16 plane (no atomics)
// 512 blocks x 256 threads; block owns 16 rows, each wave 4 rows.
__global__ __launch_bounds__(256) void k1_rows(const float* __restrict__ x,
                                               const long long* __restrict__ sub,
                                               float* __restrict__ sq,
                                               float* __restrict__ colpart,
                                               float* __restrict__ ssqpart,
                                               unsigned int* __restrict__ n0part,
                                               unsigned short* __restrict__ plane) {
    __shared__ float cls[4][256];
    __shared__ float smq[4];
    const int t = threadIdx.x;
    const int l = t & 63;
    const int w = t >> 6;
    const int base = blockIdx.x * 16;

    float4 colacc = make_float4(0.f, 0.f, 0.f, 0.f);
    float  my_sumsq = 0.f;

    // plane dest components that only depend on lane
    const int ks  = l >> 2;
    const int s16 = l & 3;
    const int lslot_add = ((s16 >> 1) << 5);
    const int lhalf_add = (s16 & 1) * 4;

    #pragma unroll
    for (int r = 0; r < 4; ++r) {
        const int row = base + w * 4 + r;
        const float4 v = ((const float4*)(x + (size_t)row * DIMS))[l];
        colacc.x += v.x; colacc.y += v.y; colacc.z += v.z; colacc.w += v.w;

        const size_t hidx = ((size_t)(row >> 5) * 16 + ks) * 512
                          + (size_t)(((row & 31) + lslot_add) * 8 + lhalf_add);
        f16x4 h = { (_Float16)v.x, (_Float16)v.y, (_Float16)v.z, (_Float16)v.w };
        *(f16x4*)(plane + hidx) = h;

        float s = v.x * v.x + v.y * v.y + v.z * v.z + v.w * v.w;
        #pragma unroll
        for (int off = 32; off; off >>= 1) s += __shfl_down(s, off, 64);
        if (l == 0) { sq[row] = s; my_sumsq += s; }
    }
    if (l == 0) smq[w] = my_sumsq;
    *(float4*)&cls[w][l * 4] = colacc;
    __syncthreads();

    colpart[blockIdx.x * 256 + t] = cls[0][t] + cls[1][t] + cls[2][t] + cls[3][t];
    if (t == 0) ssqpart[blockIdx.x] = smq[0] + smq[1] + smq[2] + smq[3];
    // n0 count: whole wave 1 participates in the ballot (wave-collective!);
    // per-lane predicate guards both the row range and the OOB load.
    if (w == 1) {
        unsigned long long m1 = __ballot(l < 16 && (int)sub[base + l] == 0);
        if (l == 0) n0part[blockIdx.x] = (unsigned int)__popcll(m1);
    }
}

// ---------------------------------------------------------------- K2: reduce partials -> scalars; init accumulators
__global__ __launch_bounds__(256) void k2_scalars(const float* __restrict__ colpart,
                                                  const float* __restrict__ ssqpart,
                                                  const unsigned int* __restrict__ n0part,
                                                  Scalars* sc) {
    __shared__ float a1[256], a2[256];
    __shared__ unsigned int a3[256];
    const int t = threadIdx.x;

    float cs = 0.f;
    #pragma unroll 8
    for (int b = 0; b < K1B; ++b) cs += colpart[b * 256 + t];   // coalesced
    a1[t] = cs * cs;
    a2[t] = ssqpart[t] + ssqpart[t + 256];
    a3[t] = n0part[t] + n0part[t + 256];
    __syncthreads();
    for (int s = 128; s; s >>= 1) {
        if (t < s) { a1[t] += a1[t + s]; a2[t] += a2[t + s]; a3[t] += a3[t + s]; }
        __syncthreads();
    }
    if (t == 0) {
        const double n = (double)N_ROWS;
        // sum(L2) = 2n*sum(sq) - 2*||colsum||^2  (diag clamp negligible)
        const double sumL2 = 2.0 * n * (double)a2[0] - 2.0 * (double)a1[0];
        const double bw = sumL2 / (n * n - n) / 4.0;   // / KERNEL_MUL^(KERNEL_NUM/2)
        sc->c2 = (float)(-1.4426950408889634 / (16.0 * bw));
        const double n0 = (double)a3[0];
        const double n1 = n - n0;
        sc->w0 = (float)( 1.0 / n0);
        sc->w1 = (float)(-1.0 / n1);
        sc->result = 0.0;
        sc->ticket = 0u;
    }
}

// ---------------------------------------------------------------- K3: fp16 MFMA Gram + kernel + reduce
// 1D triangle grid (2080 blocks, XCD-chunk swizzled). Block tile 128x128, 4 waves
// (2x2), wave tile 64x64 = 2x2 frags of 32x32x16_f16, BK=32, double-buffered
// 2x16KB LDS, staged via global_load_lds from the pre-permuted fp16 plane.
// NOTE: (256,2) only — forcing 3 waves/EU (round 3) spilled acc to scratch
// (40MB WRITE_SIZE); with ~148 regs total the HW reaches 3 blocks/CU on its own.
__global__ __launch_bounds__(256, 2) void k3_mmd(const unsigned short* __restrict__ plane,
                                                 const long long* __restrict__ sub,
                                                 const float* __restrict__ sq,
                                                 Scalars* sc,
                                                 float* __restrict__ out) {
    __shared__ char lds[32768];     // 2 x (A 8KB + B 8KB)
    __shared__ float2 sqwI[128], sqwJ[128];
    __shared__ float red4[4];

    // XCD-chunked swizzle: 2080 = 8 * 260, bijective
    const int swz = (blockIdx.x & 7) * (NBLK / 8) + (blockIdx.x >> 3);
    // decode upper-triangle tile (bi <= bj), row-major enumeration
    int bi = 0, rem = swz;
    while (rem >= NTILE - bi) { rem -= NTILE - bi; ++bi; }
    const int bj = bi + rem;
    const bool diag = (bi == bj);

    const int t  = threadIdx.x;
    const int l  = t & 63;
    const int w  = t >> 6;
    const int wr = w >> 1;
    const int wc = w & 1;

    const float c2 = sc->c2, w0 = sc->w0, w1 = sc->w1;

    // stage one BK=32 chunk (ks pair kbase,kbase+1): 16 regions x 1KB, 4 per wave
    auto stage = [&](int kbase, int bufb) {
        #pragma unroll
        for (int i = 0; i < 4; ++i) {
            const int id = w * 4 + i;
            size_t grb;
            if (id < 8) {
                grb = (size_t)((bi * 4 + (id >> 1)) * 16 + kbase + (id & 1));
            } else {
                const int ib = id - 8;
                grb = (size_t)((bj * 4 + (ib >> 1)) * 16 + kbase + (ib & 1));
            }
            const unsigned short* g = plane + grb * 512 + l * 8;   // 16B/lane
            char* lp = lds + bufb + id * 1024;                     // wave-uniform dest
            __builtin_amdgcn_global_load_lds(
                (const __attribute__((address_space(1))) unsigned int*)(const void*)g,
                (__attribute__((address_space(3))) unsigned int*)(void*)lp, 16, 0, 0);
        }
    };

    f32x16 acc[2][2] = {};
    auto compute = [&](int bufb) {
        #pragma unroll
        for (int ksL = 0; ksL < 2; ++ksL) {
            f16x8 a[2], b[2];
            #pragma unroll
            for (int m = 0; m < 2; ++m)
                a[m] = *(const f16x8*)(lds + bufb + ((wr * 2 + m) * 2 + ksL) * 1024 + l * 16);
            #pragma unroll
            for (int n = 0; n < 2; ++n)
                b[n] = *(const f16x8*)(lds + bufb + 8192 + ((wc * 2 + n) * 2 + ksL) * 1024 + l * 16);
            #pragma unroll
            for (int m = 0; m < 2; ++m)
                #pragma unroll
                for (int n = 0; n < 2; ++n)
                    acc[m][n] = __builtin_amdgcn_mfma_f32_32x32x16_f16(a[m], b[n], acc[m][n], 0, 0, 0);
        }
    };

    stage(0, 0);
    // cooperative stage of per-row (sq, weight); fold f=2 (off-diag) into I-weight
    {
        const int idx = t & 127;
        const float fold = diag ? 1.f : 2.f;
        if (t < 128) {
            const int I = bi * 128 + idx;
            const float wv = ((int)sub[I] == 0) ? w0 : w1;
            sqwI[idx] = make_float2(sq[I], wv * fold);
        } else {
            const int J = bj * 128 + idx;
            const float wv = ((int)sub[J] == 0) ? w0 : w1;
            sqwJ[idx] = make_float2(sq[J], wv);
        }
    }
    __syncthreads();

    for (int c = 0; c < 8; ++c) {
        if (c < 7) stage((c + 1) * 2, ((c + 1) & 1) * 16384);  // prefetch under compute
        compute((c & 1) * 16384);
        __syncthreads();
    }

    // ---------------- epilogue: L2 -> multi-scale kernel -> weighted partial sum
    const int lh = l >> 5;
    const int ln = l & 31;
    float sJ[2], wJ[2];
    #pragma unroll
    for (int n = 0; n < 2; ++n) {
        const float2 p = sqwJ[wc * 64 + n * 32 + ln];
        sJ[n] = p.x; wJ[n] = p.y;
    }

    float part = 0.f;
    #pragma unroll
    for (int m = 0; m < 2; ++m) {
        #pragma unroll
        for (int r = 0; r < 16; ++r) {
            // C/D layout: col = lane&31, row = (r&3) + 8*(r>>2) + 4*(lane>>5)
            const int Il = wr * 64 + m * 32 + (r & 3) + ((r >> 2) << 3) + (lh << 2);
            const float2 pi = sqwI[Il];
            #pragma unroll
            for (int n = 0; n < 2; ++n) {
                const float g = acc[m][n][r];
                float l2 = fmaxf(pi.x + sJ[n] - 2.f * g, 0.f);
                const float tt  = __builtin_amdgcn_exp2f(l2 * c2);  // exp(-L2/(16*bw))
                const float t2  = tt * tt;
                const float t4  = t2 * t2;
                const float t8  = t4 * t4;
                const float t16 = t8 * t8;
                const float K   = ((tt + t2) + (t4 + t8)) + t16;
                float w2 = pi.y * wJ[n];
                if (diag) {
                    const int Jl = wc * 64 + n * 32 + ln;
                    const float f = (Il < Jl) ? 2.f : ((Il == Jl) ? 1.f : 0.f);
                    w2 *= f;
                }
                part = fmaf(K, w2, part);
            }
        }
    }

    // wave shuffle-reduce, then 4 values via LDS (1 barrier)
    #pragma unroll
    for (int off = 32; off; off >>= 1) part += __shfl_down(part, off, 64);
    if (l == 0) red4[w] = part;
    __syncthreads();
    if (t == 0) {
        atomicAdd(&sc->result, (double)(red4[0] + red4[1] + red4[2] + red4[3]));
        __threadfence();
        const unsigned int old = atomicAdd(&sc->ticket, 1u);
        if (old == NBLK - 1) out[0] = (float)atomicAdd(&sc->result, 0.0);  // last block emits
    }
}

extern "C" void kernel_launch(void* const* d_in, const int* in_sizes, int n_in,
                              void* d_out, int out_size, void* d_ws, size_t ws_size,
                              hipStream_t stream) {
    const long long* sub = (const long long*)d_in[0];   // subggroup int64 (N,1)
    const float*     x   = (const float*)d_in[1];       // outputs fp32 (N,256)
    float* out = (float*)d_out;

    char* ws = (char*)d_ws;
    unsigned short* plane   = (unsigned short*)(ws + WS_PLANE);
    float*          sq      = (float*)(ws + WS_SQ);
    float*          colpart = (float*)(ws + WS_COLP);
    float*          ssqpart = (float*)(ws + WS_SSQ);
    unsigned int*   n0part  = (unsigned int*)(ws + WS_N0);
    Scalars*        sc      = (Scalars*)(ws + WS_SC);

    k1_rows<<<K1B, 256, 0, stream>>>(x, sub, sq, colpart, ssqpart, n0part, plane);
    k2_scalars<<<1, 256, 0, stream>>>(colpart, ssqpart, n0part, sc);
    k3_mmd<<<NBLK, 256, 0, stream>>>(plane, sub, sq, sc, out);
}

// Round 6
// 149.274 us; speedup vs baseline: 1.1885x; 1.0949x over previous
//
#include <hip/hip_runtime.h>

#define N_ROWS 8192
#define DIMS   256
#define NTILE  64                      // 8192 / 128
#define NBLK   2080                    // NTILE*(NTILE+1)/2 triangle tiles (= 8*260)
#define K1B    512                     // k1 blocks (16 rows each)

typedef _Float16 f16x4 __attribute__((ext_vector_type(4)));
typedef _Float16 f16x8 __attribute__((ext_vector_type(8)));
typedef float   f32x16 __attribute__((ext_vector_type(16)));

// ws layout:
// [0, 4MB)        : fp16 plane of x, MFMA-fragment-permuted:
//                   [rowblk=row/32][ks=k/16][slot=(row%32)+32*((k%16)/8)][(k%8)]
// [4MB, +32KB)    : float sq[8192]
// then            : colpart[K1B][256], ssqpart[K1B], n0part[K1B], Scalars
#define WS_PLANE  0
#define WS_SQ     (4 * 1024 * 1024)
#define WS_COLP   (WS_SQ + 32768)
#define WS_SSQ    (WS_COLP + K1B * 256 * 4)
#define WS_N0     (WS_SSQ + K1B * 4)
#define WS_SC     (WS_N0 + K1B * 4)

struct Scalars {
    double result;        // accumulated by k3 blocks (atomic f64)
    unsigned int ticket;  // completion counter
    float c2;             // -log2(e) / (16*bw)
    float w0;             // +1/n0
    float w1;             // -1/n1
};

// ---------------------------------------------------------------- K1: stats + fp16 plane (no atomics)
// 512 blocks x 256 threads; block owns 16 rows, each wave 4 rows.
__global__ __launch_bounds__(256) void k1_rows(const float* __restrict__ x,
                                               const long long* __restrict__ sub,
                                               float* __restrict__ sq,
                                               float* __restrict__ colpart,
                                               float* __restrict__ ssqpart,
                                               unsigned int* __restrict__ n0part,
                                               unsigned short* __restrict__ plane) {
    __shared__ float cls[4][256];
    __shared__ float smq[4];
    const int t = threadIdx.x;
    const int l = t & 63;
    const int w = t >> 6;
    const int base = blockIdx.x * 16;

    float4 colacc = make_float4(0.f, 0.f, 0.f, 0.f);
    float  my_sumsq = 0.f;

    // plane dest components that only depend on lane
    const int ks  = l >> 2;
    const int s16 = l & 3;
    const int lslot_add = ((s16 >> 1) << 5);
    const int lhalf_add = (s16 & 1) * 4;

    #pragma unroll
    for (int r = 0; r < 4; ++r) {
        const int row = base + w * 4 + r;
        const float4 v = ((const float4*)(x + (size_t)row * DIMS))[l];
        colacc.x += v.x; colacc.y += v.y; colacc.z += v.z; colacc.w += v.w;

        const size_t hidx = ((size_t)(row >> 5) * 16 + ks) * 512
                          + (size_t)(((row & 31) + lslot_add) * 8 + lhalf_add);
        f16x4 h = { (_Float16)v.x, (_Float16)v.y, (_Float16)v.z, (_Float16)v.w };
        *(f16x4*)(plane + hidx) = h;

        float s = v.x * v.x + v.y * v.y + v.z * v.z + v.w * v.w;
        #pragma unroll
        for (int off = 32; off; off >>= 1) s += __shfl_down(s, off, 64);
        if (l == 0) { sq[row] = s; my_sumsq += s; }
    }
    if (l == 0) smq[w] = my_sumsq;
    *(float4*)&cls[w][l * 4] = colacc;
    __syncthreads();

    colpart[blockIdx.x * 256 + t] = cls[0][t] + cls[1][t] + cls[2][t] + cls[3][t];
    if (t == 0) ssqpart[blockIdx.x] = smq[0] + smq[1] + smq[2] + smq[3];
    // n0: whole wave participates in ballot; per-lane predicate guards range+OOB
    if (w == 1) {
        unsigned long long m1 = __ballot(l < 16 && (int)sub[base + l] == 0);
        if (l == 0) n0part[blockIdx.x] = (unsigned int)__popcll(m1);
    }
}

// ---------------------------------------------------------------- K2: reduce partials (parallel over b)
__global__ __launch_bounds__(1024) void k2_scalars(const float* __restrict__ colpart,
                                                   const float* __restrict__ ssqpart,
                                                   const unsigned int* __restrict__ n0part,
                                                   Scalars* sc) {
    __shared__ float cp[4][256];
    __shared__ float r1[16], r2[16], r3[16];
    const int t = threadIdx.x;
    const int l = t & 63;
    const int w = t >> 6;
    const int col = t & 255;
    const int seg = t >> 8;          // 0..3, each sums 128 of the 512 partials

    float cs = 0.f;
    #pragma unroll 8
    for (int b = seg * 128; b < (seg + 1) * 128; ++b) cs += colpart[b * 256 + col];
    cp[seg][col] = cs;
    const float sv = (t < 512) ? ssqpart[t] : 0.f;
    const float nv = (t < 512) ? (float)n0part[t] : 0.f;
    __syncthreads();

    float a1 = 0.f;
    if (t < 256) {
        const float tot = cp[0][t] + cp[1][t] + cp[2][t] + cp[3][t];
        a1 = tot * tot;
    }
    float v1 = a1, v2 = sv, v3 = nv;
    #pragma unroll
    for (int off = 32; off; off >>= 1) {
        v1 += __shfl_down(v1, off, 64);
        v2 += __shfl_down(v2, off, 64);
        v3 += __shfl_down(v3, off, 64);
    }
    if (l == 0) { r1[w] = v1; r2[w] = v2; r3[w] = v3; }
    __syncthreads();
    if (t == 0) {
        double s1 = 0.0, s2 = 0.0, s3 = 0.0;
        #pragma unroll
        for (int i = 0; i < 16; ++i) { s1 += r1[i]; s2 += r2[i]; s3 += r3[i]; }
        const double n = (double)N_ROWS;
        // sum(L2) = 2n*sum(sq) - 2*||colsum||^2  (diag clamp negligible)
        const double sumL2 = 2.0 * n * s2 - 2.0 * s1;
        const double bw = sumL2 / (n * n - n) / 4.0;   // / KERNEL_MUL^(KERNEL_NUM/2)
        sc->c2 = (float)(-1.4426950408889634 / (16.0 * bw));
        const double n0 = s3;
        const double n1 = n - n0;
        sc->w0 = (float)( 1.0 / n0);
        sc->w1 = (float)(-1.0 / n1);
        sc->result = 0.0;
        sc->ticket = 0u;
    }
}

// ---------------------------------------------------------------- K3: fp16 MFMA Gram + kernel + reduce
// 1D triangle grid (2080 blocks, XCD-chunk swizzled). Block tile 128x128.
// A tile: FULL K (128x256 fp16 = 64KB) staged once into LDS -> ONE barrier total.
// 4 waves in a 1x4 grid: wave w owns J-cols [w*32, w*32+32); its B fragments are
// wave-exclusive and fragment-linear in the plane -> streamed global->VGPR
// (no LDS, no redundancy). K-loop has NO barriers: 16x {1 b-load + 4 ds_read +
// 4 MFMA}, compiler-pipelined, 4 independent acc chains.
// Epilogue sqw for the I-side overlays the (dead) A buffer after a barrier.
__global__ __launch_bounds__(256, 2) void k3_mmd(const unsigned short* __restrict__ plane,
                                                 const long long* __restrict__ sub,
                                                 const float* __restrict__ sq,
                                                 Scalars* sc,
                                                 float* __restrict__ out) {
    __shared__ char lds[65536];     // A full-K; overlaid by sqwI + red4 in epilogue

    // XCD-chunked swizzle: 2080 = 8 * 260, bijective
    const int swz = (blockIdx.x & 7) * (NBLK / 8) + (blockIdx.x >> 3);
    // decode upper-triangle tile (bi <= bj), row-major enumeration
    int bi = 0, rem = swz;
    while (rem >= NTILE - bi) { rem -= NTILE - bi; ++bi; }
    const int bj = bi + rem;
    const bool diag = (bi == bj);

    const int t  = threadIdx.x;
    const int l  = t & 63;
    const int w  = t >> 6;        // wave = J-column group (1x4 wave grid)
    const int lh = l >> 5;
    const int ln = l & 31;

    const float c2 = sc->c2, w0 = sc->w0, w1 = sc->w1;

    // ---- stage A full-K: wave w stages rowblk rb = w (16 regions x 1KB)
    #pragma unroll
    for (int i = 0; i < 16; ++i) {
        const unsigned short* g = plane + (((size_t)(bi * 4 + w) * 16 + i) << 9) + (l << 3);
        char* lp = lds + ((w * 16 + i) << 10);    // wave-uniform dest + lane*16
        __builtin_amdgcn_global_load_lds(
            (const __attribute__((address_space(1))) unsigned int*)(const void*)g,
            (__attribute__((address_space(3))) unsigned int*)(void*)lp, 16, 0, 0);
    }

    // ---- J-side scalars straight to registers (wave-exclusive cols)
    const int J = bj * 128 + w * 32 + ln;
    const float sJ = sq[J];
    const float wJ = ((int)sub[J] == 0) ? w0 : w1;

    __syncthreads();   // the ONLY pre-compute barrier (drains A staging)

    // ---- K-loop: no barriers
    f32x16 acc[4] = {};
    const size_t brb = ((size_t)(bj * 4 + w) * 16) << 9;
    #pragma unroll
    for (int ks = 0; ks < 16; ++ks) {
        const f16x8 b = *(const f16x8*)(plane + brb + ((size_t)ks << 9) + (l << 3));
        #pragma unroll
        for (int m = 0; m < 4; ++m) {
            const f16x8 a = *(const f16x8*)(lds + ((m * 16 + ks) << 10) + (l << 4));
            acc[m] = __builtin_amdgcn_mfma_f32_32x32x16_f16(a, b, acc[m], 0, 0, 0);
        }
    }

    // ---- re-stage I-side (sq, weight) over the dead A buffer
    __syncthreads();   // all A reads done
    float2* sqwI = (float2*)lds;
    float*  redw = (float*)(lds + 1024);
    if (t < 128) {
        const int I = bi * 128 + t;
        const float wv = ((int)sub[I] == 0) ? w0 : w1;
        sqwI[t] = make_float2(sq[I], wv * (diag ? 1.f : 2.f));
    }
    __syncthreads();

    // ---- epilogue: L2 -> multi-scale kernel -> weighted partial sum
    float part = 0.f;
    #pragma unroll
    for (int m = 0; m < 4; ++m) {
        #pragma unroll
        for (int r = 0; r < 16; ++r) {
            // C/D layout: col = lane&31, row = (r&3) + 8*(r>>2) + 4*(lane>>5)
            const int Il = m * 32 + (r & 3) + ((r >> 2) << 3) + (lh << 2);
            const float2 pi = sqwI[Il];
            const float g = acc[m][r];
            float l2 = fmaxf(pi.x + sJ - 2.f * g, 0.f);
            const float tt  = __builtin_amdgcn_exp2f(l2 * c2);  // exp(-L2/(16*bw))
            const float t2  = tt * tt;
            const float t4  = t2 * t2;
            const float t8  = t4 * t4;
            const float t16 = t8 * t8;
            const float K   = ((tt + t2) + (t4 + t8)) + t16;
            float w2 = pi.y * wJ;
            if (diag) {
                const int Jl = w * 32 + ln;
                const float f = (Il < Jl) ? 2.f : ((Il == Jl) ? 1.f : 0.f);
                w2 *= f;
            }
            part = fmaf(K, w2, part);
        }
    }

    // wave shuffle-reduce, then 4 values via LDS (1 barrier)
    #pragma unroll
    for (int off = 32; off; off >>= 1) part += __shfl_down(part, off, 64);
    if (l == 0) redw[w] = part;
    __syncthreads();
    if (t == 0) {
        atomicAdd(&sc->result, (double)(redw[0] + redw[1] + redw[2] + redw[3]));
        __threadfence();
        const unsigned int old = atomicAdd(&sc->ticket, 1u);
        if (old == NBLK - 1) out[0] = (float)atomicAdd(&sc->result, 0.0);  // last block emits
    }
}

extern "C" void kernel_launch(void* const* d_in, const int* in_sizes, int n_in,
                              void* d_out, int out_size, void* d_ws, size_t ws_size,
                              hipStream_t stream) {
    const long long* sub = (const long long*)d_in[0];   // subggroup int64 (N,1)
    const float*     x   = (const float*)d_in[1];       // outputs fp32 (N,256)
    float* out = (float*)d_out;

    char* ws = (char*)d_ws;
    unsigned short* plane   = (unsigned short*)(ws + WS_PLANE);
    float*          sq      = (float*)(ws + WS_SQ);
    float*          colpart = (float*)(ws + WS_COLP);
    float*          ssqpart = (float*)(ws + WS_SSQ);
    unsigned int*   n0part  = (unsigned int*)(ws + WS_N0);
    Scalars*        sc      = (Scalars*)(ws + WS_SC);

    k1_rows<<<K1B, 256, 0, stream>>>(x, sub, sq, colpart, ssqpart, n0part, plane);
    k2_scalars<<<1, 1024, 0, stream>>>(colpart, ssqpart, n0part, sc);
    k3_mmd<<<NBLK, 256, 0, stream>>>(plane, sub, sq, sc, out);
}

// Round 7
// 147.001 us; speedup vs baseline: 1.2069x; 1.0155x over previous
//
#include <hip/hip_runtime.h>

#define N_ROWS 8192
#define DIMS   256
#define NTILE  64                      // 8192 / 128
#define NBLK   2080                    // NTILE*(NTILE+1)/2 triangle tiles (= 8*260)
#define K1B    512                     // k1 blocks (16 rows each)

typedef _Float16 f16x4 __attribute__((ext_vector_type(4)));
typedef _Float16 f16x8 __attribute__((ext_vector_type(8)));
typedef float   f32x16 __attribute__((ext_vector_type(16)));

// ws layout:
// [0, 4MB)        : fp16 plane of x, MFMA-fragment-permuted:
//                   [rowblk=row/32][ks=k/16][slot=(row%32)+32*((k%16)/8)][(k%8)]
// [4MB, +32KB)    : float sq[8192]
// then            : colpart[K1B][256], ssqpart[K1B], n0part[K1B], Scalars
#define WS_PLANE  0
#define WS_SQ     (4 * 1024 * 1024)
#define WS_COLP   (WS_SQ + 32768)
#define WS_SSQ    (WS_COLP + K1B * 256 * 4)
#define WS_N0     (WS_SSQ + K1B * 4)
#define WS_SC     (WS_N0 + K1B * 4)

struct Scalars {
    double result;        // accumulated by k3 blocks (atomic f64)
    unsigned int ticket;  // completion counter
    float c2;             // -log2(e) / (16*bw)
    float w0;             // +1/n0
    float w1;             // -1/n1
};

// ---------------------------------------------------------------- K1: stats + fp16 plane (no atomics)
// 512 blocks x 256 threads; block owns 16 rows, each wave 4 rows.
__global__ __launch_bounds__(256) void k1_rows(const float* __restrict__ x,
                                               const long long* __restrict__ sub,
                                               float* __restrict__ sq,
                                               float* __restrict__ colpart,
                                               float* __restrict__ ssqpart,
                                               unsigned int* __restrict__ n0part,
                                               unsigned short* __restrict__ plane) {
    __shared__ float cls[4][256];
    __shared__ float smq[4];
    const int t = threadIdx.x;
    const int l = t & 63;
    const int w = t >> 6;
    const int base = blockIdx.x * 16;

    float4 colacc = make_float4(0.f, 0.f, 0.f, 0.f);
    float  my_sumsq = 0.f;

    // plane dest components that only depend on lane
    const int ks  = l >> 2;
    const int s16 = l & 3;
    const int lslot_add = ((s16 >> 1) << 5);
    const int lhalf_add = (s16 & 1) * 4;

    #pragma unroll
    for (int r = 0; r < 4; ++r) {
        const int row = base + w * 4 + r;
        const float4 v = ((const float4*)(x + (size_t)row * DIMS))[l];
        colacc.x += v.x; colacc.y += v.y; colacc.z += v.z; colacc.w += v.w;

        const size_t hidx = ((size_t)(row >> 5) * 16 + ks) * 512
                          + (size_t)(((row & 31) + lslot_add) * 8 + lhalf_add);
        f16x4 h = { (_Float16)v.x, (_Float16)v.y, (_Float16)v.z, (_Float16)v.w };
        *(f16x4*)(plane + hidx) = h;

        float s = v.x * v.x + v.y * v.y + v.z * v.z + v.w * v.w;
        #pragma unroll
        for (int off = 32; off; off >>= 1) s += __shfl_down(s, off, 64);
        if (l == 0) { sq[row] = s; my_sumsq += s; }
    }
    if (l == 0) smq[w] = my_sumsq;
    *(float4*)&cls[w][l * 4] = colacc;
    __syncthreads();

    colpart[blockIdx.x * 256 + t] = cls[0][t] + cls[1][t] + cls[2][t] + cls[3][t];
    if (t == 0) ssqpart[blockIdx.x] = smq[0] + smq[1] + smq[2] + smq[3];
    // n0: whole wave participates in ballot; per-lane predicate guards range+OOB
    if (w == 1) {
        unsigned long long m1 = __ballot(l < 16 && (int)sub[base + l] == 0);
        if (l == 0) n0part[blockIdx.x] = (unsigned int)__popcll(m1);
    }
}

// ---------------------------------------------------------------- K2: reduce partials (parallel over b)
__global__ __launch_bounds__(1024) void k2_scalars(const float* __restrict__ colpart,
                                                   const float* __restrict__ ssqpart,
                                                   const unsigned int* __restrict__ n0part,
                                                   Scalars* sc) {
    __shared__ float cp[4][256];
    __shared__ float r1[16], r2[16], r3[16];
    const int t = threadIdx.x;
    const int l = t & 63;
    const int w = t >> 6;
    const int col = t & 255;
    const int seg = t >> 8;          // 0..3, each sums 128 of the 512 partials

    float cs = 0.f;
    #pragma unroll 8
    for (int b = seg * 128; b < (seg + 1) * 128; ++b) cs += colpart[b * 256 + col];
    cp[seg][col] = cs;
    const float sv = (t < 512) ? ssqpart[t] : 0.f;
    const float nv = (t < 512) ? (float)n0part[t] : 0.f;
    __syncthreads();

    float a1 = 0.f;
    if (t < 256) {
        const float tot = cp[0][t] + cp[1][t] + cp[2][t] + cp[3][t];
        a1 = tot * tot;
    }
    float v1 = a1, v2 = sv, v3 = nv;
    #pragma unroll
    for (int off = 32; off; off >>= 1) {
        v1 += __shfl_down(v1, off, 64);
        v2 += __shfl_down(v2, off, 64);
        v3 += __shfl_down(v3, off, 64);
    }
    if (l == 0) { r1[w] = v1; r2[w] = v2; r3[w] = v3; }
    __syncthreads();
    if (t == 0) {
        double s1 = 0.0, s2 = 0.0, s3 = 0.0;
        #pragma unroll
        for (int i = 0; i < 16; ++i) { s1 += r1[i]; s2 += r2[i]; s3 += r3[i]; }
        const double n = (double)N_ROWS;
        // sum(L2) = 2n*sum(sq) - 2*||colsum||^2  (diag clamp negligible)
        const double sumL2 = 2.0 * n * s2 - 2.0 * s1;
        const double bw = sumL2 / (n * n - n) / 4.0;   // / KERNEL_MUL^(KERNEL_NUM/2)
        sc->c2 = (float)(-1.4426950408889634 / (16.0 * bw));
        const double n0 = s3;
        const double n1 = n - n0;
        sc->w0 = (float)( 1.0 / n0);
        sc->w1 = (float)(-1.0 / n1);
        sc->result = 0.0;
        sc->ticket = 0u;
    }
}

// ---------------------------------------------------------------- K3: fp16 MFMA Gram + kernel + reduce
// 1D triangle grid (2080 blocks, XCD-chunk swizzled). Block tile 128x128.
// A: FULL-K (128x256 fp16 = 64KB) via global_load_lds, issued first.
// B: ALL 16 fragments preloaded to registers (64 VGPR), issued BEFORE the single
// __syncthreads -> its vmcnt(0) drain covers A-DMA + B together = ONE latency
// window per block (round 6 had 16 serial windows; that was the 81 us).
// K-loop touches only LDS+MFMA: 16 x {4 ds_read_b128 + 4 MFMA}, 4 indep chains.
// Regs ~190 unified -> 2 waves/SIMD; LDS 64KB -> 2 blocks/CU. Balanced at 25%.
__global__ __launch_bounds__(256, 2) void k3_mmd(const unsigned short* __restrict__ plane,
                                                 const long long* __restrict__ sub,
                                                 const float* __restrict__ sq,
                                                 Scalars* sc,
                                                 float* __restrict__ out) {
    __shared__ char lds[65536];     // A full-K; overlaid by sqwI + red in epilogue

    // XCD-chunked swizzle: 2080 = 8 * 260, bijective
    const int swz = (blockIdx.x & 7) * (NBLK / 8) + (blockIdx.x >> 3);
    // decode upper-triangle tile (bi <= bj), row-major enumeration
    int bi = 0, rem = swz;
    while (rem >= NTILE - bi) { rem -= NTILE - bi; ++bi; }
    const int bj = bi + rem;
    const bool diag = (bi == bj);

    const int t  = threadIdx.x;
    const int l  = t & 63;
    const int w  = t >> 6;        // wave = J-column group (1x4 wave grid)
    const int lh = l >> 5;
    const int ln = l & 31;

    const float c2 = sc->c2, w0 = sc->w0, w1 = sc->w1;

    // ---- issue A full-K staging first: wave w stages rowblk rb = w (16 x 1KB)
    #pragma unroll
    for (int i = 0; i < 16; ++i) {
        const unsigned short* g = plane + (((size_t)(bi * 4 + w) * 16 + i) << 9) + (l << 3);
        char* lp = lds + ((w * 16 + i) << 10);    // wave-uniform dest + lane*16
        __builtin_amdgcn_global_load_lds(
            (const __attribute__((address_space(1))) unsigned int*)(const void*)g,
            (__attribute__((address_space(3))) unsigned int*)(void*)lp, 16, 0, 0);
    }

    // ---- preload ALL B fragments to registers (wave-exclusive cols), in the
    // shadow of the A-DMA; fully unrolled -> compile-time indices (no scratch)
    const size_t brb = ((size_t)(bj * 4 + w) * 16) << 9;
    f16x8 b[16];
    #pragma unroll
    for (int ks = 0; ks < 16; ++ks)
        b[ks] = *(const f16x8*)(plane + brb + ((size_t)ks << 9) + (l << 3));

    // ---- J-side scalars straight to registers (wave-exclusive cols)
    const int J = bj * 128 + w * 32 + ln;
    const float sJ = sq[J];
    const float wJ = ((int)sub[J] == 0) ? w0 : w1;

    __syncthreads();   // ONE latency window: drains A-DMA + b[] + sJ/wJ loads

    // ---- K-loop: LDS + MFMA only, no barriers, 4 independent acc chains
    f32x16 acc[4] = {};
    #pragma unroll
    for (int ks = 0; ks < 16; ++ks) {
        #pragma unroll
        for (int m = 0; m < 4; ++m) {
            const f16x8 a = *(const f16x8*)(lds + ((m * 16 + ks) << 10) + (l << 4));
            acc[m] = __builtin_amdgcn_mfma_f32_32x32x16_f16(a, b[ks], acc[m], 0, 0, 0);
        }
    }

    // ---- re-stage I-side (sq, weight) over the dead A buffer
    __syncthreads();   // all A reads done
    float2* sqwI = (float2*)lds;
    float*  redw = (float*)(lds + 1024);
    if (t < 128) {
        const int I = bi * 128 + t;
        const float wv = ((int)sub[I] == 0) ? w0 : w1;
        sqwI[t] = make_float2(sq[I], wv * (diag ? 1.f : 2.f));
    }
    __syncthreads();

    // ---- epilogue: L2 -> multi-scale kernel -> weighted partial sum
    float part = 0.f;
    #pragma unroll
    for (int m = 0; m < 4; ++m) {
        #pragma unroll
        for (int r = 0; r < 16; ++r) {
            // C/D layout: col = lane&31, row = (r&3) + 8*(r>>2) + 4*(lane>>5)
            const int Il = m * 32 + (r & 3) + ((r >> 2) << 3) + (lh << 2);
            const float2 pi = sqwI[Il];
            const float g = acc[m][r];
            float l2 = fmaxf(pi.x + sJ - 2.f * g, 0.f);
            const float tt  = __builtin_amdgcn_exp2f(l2 * c2);  // exp(-L2/(16*bw))
            const float t2  = tt * tt;
            const float t4  = t2 * t2;
            const float t8  = t4 * t4;
            const float t16 = t8 * t8;
            const float K   = ((tt + t2) + (t4 + t8)) + t16;
            float w2 = pi.y * wJ;
            if (diag) {
                const int Jl = w * 32 + ln;
                const float f = (Il < Jl) ? 2.f : ((Il == Jl) ? 1.f : 0.f);
                w2 *= f;
            }
            part = fmaf(K, w2, part);
        }
    }

    // wave shuffle-reduce, then 4 values via LDS (1 barrier)
    #pragma unroll
    for (int off = 32; off; off >>= 1) part += __shfl_down(part, off, 64);
    if (l == 0) redw[w] = part;
    __syncthreads();
    if (t == 0) {
        atomicAdd(&sc->result, (double)(redw[0] + redw[1] + redw[2] + redw[3]));
        __threadfence();
        const unsigned int old = atomicAdd(&sc->ticket, 1u);
        if (old == NBLK - 1) out[0] = (float)atomicAdd(&sc->result, 0.0);  // last block emits
    }
}

extern "C" void kernel_launch(void* const* d_in, const int* in_sizes, int n_in,
                              void* d_out, int out_size, void* d_ws, size_t ws_size,
                              hipStream_t stream) {
    const long long* sub = (const long long*)d_in[0];   // subggroup int64 (N,1)
    const float*     x   = (const float*)d_in[1];       // outputs fp32 (N,256)
    float* out = (float*)d_out;

    char* ws = (char*)d_ws;
    unsigned short* plane   = (unsigned short*)(ws + WS_PLANE);
    float*          sq      = (float*)(ws + WS_SQ);
    float*          colpart = (float*)(ws + WS_COLP);
    float*          ssqpart = (float*)(ws + WS_SSQ);
    unsigned int*   n0part  = (unsigned int*)(ws + WS_N0);
    Scalars*        sc      = (Scalars*)(ws + WS_SC);

    k1_rows<<<K1B, 256, 0, stream>>>(x, sub, sq, colpart, ssqpart, n0part, plane);
    k2_scalars<<<1, 1024, 0, stream>>>(colpart, ssqpart, n0part, sc);
    k3_mmd<<<NBLK, 256, 0, stream>>>(plane, sub, sq, sc, out);
}

// Round 8
// 145.493 us; speedup vs baseline: 1.2194x; 1.0104x over previous
//
#include <hip/hip_runtime.h>

#define N_ROWS 8192
#define DIMS   256
#define NTILE  64                      // 8192 / 128
#define NBLK   2080                    // NTILE*(NTILE+1)/2 triangle tiles (= 8*260)
#define K1B    512                     // k1 blocks (16 rows each)

typedef _Float16 f16x4 __attribute__((ext_vector_type(4)));
typedef _Float16 f16x8 __attribute__((ext_vector_type(8)));
typedef float   f32x16 __attribute__((ext_vector_type(16)));

// ws layout:
// [0, 4MB)        : fp16 plane of x, MFMA-fragment-permuted:
//                   [rowblk=row/32][ks=k/16][slot=(row%32)+32*((k%16)/8)][(k%8)]
// [4MB, +32KB)    : float sq[8192]
// then            : colpart[K1B][256], ssqpart[K1B], n0part[K1B], Scalars, partial[NBLK]
#define WS_PLANE  0
#define WS_SQ     (4 * 1024 * 1024)
#define WS_COLP   (WS_SQ + 32768)
#define WS_SSQ    (WS_COLP + K1B * 256 * 4)
#define WS_N0     (WS_SSQ + K1B * 4)
#define WS_SC     (WS_N0 + K1B * 4)
#define WS_PART   (WS_SC + 64)

struct Scalars {
    unsigned int ticket;  // completion counter
    float c2;             // -log2(e) / (16*bw)
    float w0;             // +1/n0
    float w1;             // -1/n1
};

// ---------------------------------------------------------------- K1: stats + fp16 plane (no atomics)
// 512 blocks x 256 threads; block owns 16 rows, each wave 4 rows.
__global__ __launch_bounds__(256) void k1_rows(const float* __restrict__ x,
                                               const long long* __restrict__ sub,
                                               float* __restrict__ sq,
                                               float* __restrict__ colpart,
                                               float* __restrict__ ssqpart,
                                               unsigned int* __restrict__ n0part,
                                               unsigned short* __restrict__ plane) {
    __shared__ float cls[4][256];
    __shared__ float smq[4];
    const int t = threadIdx.x;
    const int l = t & 63;
    const int w = t >> 6;
    const int base = blockIdx.x * 16;

    float4 colacc = make_float4(0.f, 0.f, 0.f, 0.f);
    float  my_sumsq = 0.f;

    // plane dest components that only depend on lane
    const int ks  = l >> 2;
    const int s16 = l & 3;
    const int lslot_add = ((s16 >> 1) << 5);
    const int lhalf_add = (s16 & 1) * 4;

    #pragma unroll
    for (int r = 0; r < 4; ++r) {
        const int row = base + w * 4 + r;
        const float4 v = ((const float4*)(x + (size_t)row * DIMS))[l];
        colacc.x += v.x; colacc.y += v.y; colacc.z += v.z; colacc.w += v.w;

        const size_t hidx = ((size_t)(row >> 5) * 16 + ks) * 512
                          + (size_t)(((row & 31) + lslot_add) * 8 + lhalf_add);
        f16x4 h = { (_Float16)v.x, (_Float16)v.y, (_Float16)v.z, (_Float16)v.w };
        *(f16x4*)(plane + hidx) = h;

        float s = v.x * v.x + v.y * v.y + v.z * v.z + v.w * v.w;
        #pragma unroll
        for (int off = 32; off; off >>= 1) s += __shfl_down(s, off, 64);
        if (l == 0) { sq[row] = s; my_sumsq += s; }
    }
    if (l == 0) smq[w] = my_sumsq;
    *(float4*)&cls[w][l * 4] = colacc;
    __syncthreads();

    colpart[blockIdx.x * 256 + t] = cls[0][t] + cls[1][t] + cls[2][t] + cls[3][t];
    if (t == 0) ssqpart[blockIdx.x] = smq[0] + smq[1] + smq[2] + smq[3];
    // n0: whole wave participates in ballot; per-lane predicate guards range+OOB
    if (w == 1) {
        unsigned long long m1 = __ballot(l < 16 && (int)sub[base + l] == 0);
        if (l == 0) n0part[blockIdx.x] = (unsigned int)__popcll(m1);
    }
}

// ---------------------------------------------------------------- K2: reduce partials (parallel over b)
__global__ __launch_bounds__(1024) void k2_scalars(const float* __restrict__ colpart,
                                                   const float* __restrict__ ssqpart,
                                                   const unsigned int* __restrict__ n0part,
                                                   Scalars* sc) {
    __shared__ float cp[4][256];
    __shared__ float r1[16], r2[16], r3[16];
    const int t = threadIdx.x;
    const int l = t & 63;
    const int w = t >> 6;
    const int col = t & 255;
    const int seg = t >> 8;          // 0..3, each sums 128 of the 512 partials

    float cs = 0.f;
    #pragma unroll 8
    for (int b = seg * 128; b < (seg + 1) * 128; ++b) cs += colpart[b * 256 + col];
    cp[seg][col] = cs;
    const float sv = (t < 512) ? ssqpart[t] : 0.f;
    const float nv = (t < 512) ? (float)n0part[t] : 0.f;
    __syncthreads();

    float a1 = 0.f;
    if (t < 256) {
        const float tot = cp[0][t] + cp[1][t] + cp[2][t] + cp[3][t];
        a1 = tot * tot;
    }
    float v1 = a1, v2 = sv, v3 = nv;
    #pragma unroll
    for (int off = 32; off; off >>= 1) {
        v1 += __shfl_down(v1, off, 64);
        v2 += __shfl_down(v2, off, 64);
        v3 += __shfl_down(v3, off, 64);
    }
    if (l == 0) { r1[w] = v1; r2[w] = v2; r3[w] = v3; }
    __syncthreads();
    if (t == 0) {
        double s1 = 0.0, s2 = 0.0, s3 = 0.0;
        #pragma unroll
        for (int i = 0; i < 16; ++i) { s1 += r1[i]; s2 += r2[i]; s3 += r3[i]; }
        const double n = (double)N_ROWS;
        // sum(L2) = 2n*sum(sq) - 2*||colsum||^2  (diag clamp negligible)
        const double sumL2 = 2.0 * n * s2 - 2.0 * s1;
        const double bw = sumL2 / (n * n - n) / 4.0;   // / KERNEL_MUL^(KERNEL_NUM/2)
        sc->c2 = (float)(-1.4426950408889634 / (16.0 * bw));
        const double n0 = s3;
        const double n1 = n - n0;
        sc->w0 = (float)( 1.0 / n0);
        sc->w1 = (float)(-1.0 / n1);
        sc->ticket = 0u;
    }
}

// ---------------------------------------------------------------- K3: fp16 MFMA Gram + kernel + reduce
// 1D triangle grid (2080 blocks, XCD-chunk swizzled). Block tile 128x128.
// A: FULL-K (128x256 fp16 = 64KB) via global_load_lds, issued first.
// B: ALL 16 fragments preloaded to registers — PINNED with "+v" asm so the
// compiler cannot sink the loads back into the K-loop (round 7 failed exactly
// this way: VGPR stayed 88, loads re-sunk, 16 serial latency windows remained).
// K-loop touches only LDS+MFMA. Result: per-block plain store to partial[];
// last block (ticket) reduces partials -> out. No same-address f64 atomics.
__global__ __launch_bounds__(256, 2) void k3_mmd(const unsigned short* __restrict__ plane,
                                                 const long long* __restrict__ sub,
                                                 const float* __restrict__ sq,
                                                 Scalars* sc,
                                                 float* __restrict__ partial,
                                                 float* __restrict__ out) {
    __shared__ char lds[65536];     // A full-K; overlaid in epilogue (64KB cap!)

    // XCD-chunked swizzle: 2080 = 8 * 260, bijective
    const int swz = (blockIdx.x & 7) * (NBLK / 8) + (blockIdx.x >> 3);
    // decode upper-triangle tile (bi <= bj), row-major enumeration
    int bi = 0, rem = swz;
    while (rem >= NTILE - bi) { rem -= NTILE - bi; ++bi; }
    const int bj = bi + rem;
    const bool diag = (bi == bj);

    const int t  = threadIdx.x;
    const int l  = t & 63;
    const int w  = t >> 6;        // wave = J-column group (1x4 wave grid)
    const int lh = l >> 5;
    const int ln = l & 31;

    const float c2 = sc->c2, w0 = sc->w0, w1 = sc->w1;

    // ---- issue A full-K staging first: wave w stages rowblk rb = w (16 x 1KB)
    #pragma unroll
    for (int i = 0; i < 16; ++i) {
        const unsigned short* g = plane + (((size_t)(bi * 4 + w) * 16 + i) << 9) + (l << 3);
        char* lp = lds + ((w * 16 + i) << 10);    // wave-uniform dest + lane*16
        __builtin_amdgcn_global_load_lds(
            (const __attribute__((address_space(1))) unsigned int*)(const void*)g,
            (__attribute__((address_space(3))) unsigned int*)(void*)lp, 16, 0, 0);
    }

    // ---- preload ALL B fragments to registers (wave-exclusive cols), in the
    // shadow of the A-DMA, then PIN them ("+v": MFMA must consume the asm's
    // register output, so the loads cannot be sunk past this point)
    const size_t brb = ((size_t)(bj * 4 + w) * 16) << 9;
    f16x8 b[16];
    #pragma unroll
    for (int ks = 0; ks < 16; ++ks)
        b[ks] = *(const f16x8*)(plane + brb + ((size_t)ks << 9) + (l << 3));
    #pragma unroll
    for (int ks = 0; ks < 16; ++ks)
        asm volatile("" : "+v"(b[ks]));
    __builtin_amdgcn_sched_barrier(0);

    // ---- J-side scalars straight to registers (wave-exclusive cols)
    const int J = bj * 128 + w * 32 + ln;
    const float sJ = sq[J];
    const float wJ = ((int)sub[J] == 0) ? w0 : w1;

    __syncthreads();   // ONE latency window: drains A-DMA (+ b[] already forced)

    // ---- K-loop: LDS + MFMA only, no barriers, 4 independent acc chains
    f32x16 acc[4] = {};
    #pragma unroll
    for (int ks = 0; ks < 16; ++ks) {
        #pragma unroll
        for (int m = 0; m < 4; ++m) {
            const f16x8 a = *(const f16x8*)(lds + ((m * 16 + ks) << 10) + (l << 4));
            acc[m] = __builtin_amdgcn_mfma_f32_32x32x16_f16(a, b[ks], acc[m], 0, 0, 0);
        }
    }

    // ---- re-stage I-side (sq, weight) over the dead A buffer
    __syncthreads();   // all A reads done
    float2* sqwI = (float2*)lds;
    float*  redw = (float*)(lds + 1024);
    if (t < 128) {
        const int I = bi * 128 + t;
        const float wv = ((int)sub[I] == 0) ? w0 : w1;
        sqwI[t] = make_float2(sq[I], wv * (diag ? 1.f : 2.f));
    }
    __syncthreads();

    // ---- epilogue: L2 -> multi-scale kernel -> weighted partial sum
    float part = 0.f;
    #pragma unroll
    for (int m = 0; m < 4; ++m) {
        #pragma unroll
        for (int r = 0; r < 16; ++r) {
            // C/D layout: col = lane&31, row = (r&3) + 8*(r>>2) + 4*(lane>>5)
            const int Il = m * 32 + (r & 3) + ((r >> 2) << 3) + (lh << 2);
            const float2 pi = sqwI[Il];
            const float g = acc[m][r];
            float l2 = fmaxf(pi.x + sJ - 2.f * g, 0.f);
            const float tt  = __builtin_amdgcn_exp2f(l2 * c2);  // exp(-L2/(16*bw))
            const float t2  = tt * tt;
            const float t4  = t2 * t2;
            const float t8  = t4 * t4;
            const float t16 = t8 * t8;
            const float K   = ((tt + t2) + (t4 + t8)) + t16;
            float w2 = pi.y * wJ;
            if (diag) {
                const int Jl = w * 32 + ln;
                const float f = (Il < Jl) ? 2.f : ((Il == Jl) ? 1.f : 0.f);
                w2 *= f;
            }
            part = fmaf(K, w2, part);
        }
    }

    // wave shuffle-reduce, then 4 values via LDS
    #pragma unroll
    for (int off = 32; off; off >>= 1) part += __shfl_down(part, off, 64);
    if (l == 0) redw[w] = part;
    __syncthreads();

    // ---- per-block plain store + ticket; last block reduces all partials
    unsigned int* flag = (unsigned int*)(lds + 2048);
    if (t == 0) {
        partial[blockIdx.x] = redw[0] + redw[1] + redw[2] + redw[3];
        __threadfence();   // release: partial visible before ticket bump
        *flag = (atomicAdd(&sc->ticket, 1u) == NBLK - 1) ? 1u : 0u;
    }
    __syncthreads();
    if (*flag) {           // block-uniform
        __threadfence();   // acquire: see all producers' partials
        double v = 0.0;
        for (int i = t; i < NBLK; i += 256) v += (double)partial[i];
        #pragma unroll
        for (int off = 32; off; off >>= 1) v += __shfl_down(v, off, 64);
        double* dd = (double*)(lds + 2112);
        if (l == 0) dd[w] = v;
        __syncthreads();
        if (t == 0) out[0] = (float)(dd[0] + dd[1] + dd[2] + dd[3]);
    }
}

extern "C" void kernel_launch(void* const* d_in, const int* in_sizes, int n_in,
                              void* d_out, int out_size, void* d_ws, size_t ws_size,
                              hipStream_t stream) {
    const long long* sub = (const long long*)d_in[0];   // subggroup int64 (N,1)
    const float*     x   = (const float*)d_in[1];       // outputs fp32 (N,256)
    float* out = (float*)d_out;

    char* ws = (char*)d_ws;
    unsigned short* plane   = (unsigned short*)(ws + WS_PLANE);
    float*          sq      = (float*)(ws + WS_SQ);
    float*          colpart = (float*)(ws + WS_COLP);
    float*          ssqpart = (float*)(ws + WS_SSQ);
    unsigned int*   n0part  = (unsigned int*)(ws + WS_N0);
    Scalars*        sc      = (Scalars*)(ws + WS_SC);
    float*          partial = (float*)(ws + WS_PART);

    k1_rows<<<K1B, 256, 0, stream>>>(x, sub, sq, colpart, ssqpart, n0part, plane);
    k2_scalars<<<1, 1024, 0, stream>>>(colpart, ssqpart, n0part, sc);
    k3_mmd<<<NBLK, 256, 0, stream>>>(plane, sub, sq, sc, partial, out);
}

// Round 10
// 125.381 us; speedup vs baseline: 1.4150x; 1.1604x over previous
//
#include <hip/hip_runtime.h>

#define N_ROWS 8192
#define DIMS   256
#define NTILE  64                      // 8192 / 128
#define NCHUNK 544                     // sum over bi of ceil((64-bi)/4)
#define K1B    512                     // k1 blocks (16 rows each)
#define K3B    512                     // k3 blocks (2 per CU)

typedef _Float16 f16x4 __attribute__((ext_vector_type(4)));
typedef _Float16 f16x8 __attribute__((ext_vector_type(8)));
typedef float   f32x16 __attribute__((ext_vector_type(16)));

// ws layout:
// [0, 4MB)   : fp16 plane of x, MFMA-fragment-permuted
// [4MB,+32KB): float sq[8192]
// then       : colpart[K1B][256], ssqpart[K1B], n0part[K1B], Scalars, partial[K3B]
#define WS_PLANE  0
#define WS_SQ     (4 * 1024 * 1024)
#define WS_COLP   (WS_SQ + 32768)
#define WS_SSQ    (WS_COLP + K1B * 256 * 4)
#define WS_N0     (WS_SSQ + K1B * 4)
#define WS_SC     (WS_N0 + K1B * 4)
#define WS_PART   (WS_SC + 64)

struct Scalars {
    unsigned int ctr;     // k3 chunk-queue head   (zeroed by k2 each launch)
    unsigned int t3;      // k3 completion ticket  (zeroed by k2 each launch)
    float c2;             // -log2(e) / (16*bw)
    float w0;             // +1/n0
    float w1;             // -1/n1
};

// real asm load: cannot be sunk/split/rematerialized by the scheduler
// (compiler-level pins failed to hold the preload in rounds 6-8: VGPR stayed 88)
#define BL(dst, p, o) asm volatile("global_load_dwordx4 %0, %1, off offset:" o \
                                   : "=v"(dst) : "v"(p))

// ---------------------------------------------------------------- K1: stats + fp16 plane (round-8 proven)
__global__ __launch_bounds__(256) void k1_rows(const float* __restrict__ x,
                                               const long long* __restrict__ sub,
                                               float* __restrict__ sq,
                                               float* __restrict__ colpart,
                                               float* __restrict__ ssqpart,
                                               unsigned int* __restrict__ n0part,
                                               unsigned short* __restrict__ plane) {
    __shared__ float cls[4][256];
    __shared__ float smq[4];
    const int t = threadIdx.x;
    const int l = t & 63;
    const int w = t >> 6;
    const int base = blockIdx.x * 16;

    float4 colacc = make_float4(0.f, 0.f, 0.f, 0.f);
    float  my_sumsq = 0.f;

    const int ks  = l >> 2;
    const int s16 = l & 3;
    const int lslot_add = ((s16 >> 1) << 5);
    const int lhalf_add = (s16 & 1) * 4;

    #pragma unroll
    for (int r = 0; r < 4; ++r) {
        const int row = base + w * 4 + r;
        const float4 v = ((const float4*)(x + (size_t)row * DIMS))[l];
        colacc.x += v.x; colacc.y += v.y; colacc.z += v.z; colacc.w += v.w;

        const size_t hidx = ((size_t)(row >> 5) * 16 + ks) * 512
                          + (size_t)(((row & 31) + lslot_add) * 8 + lhalf_add);
        f16x4 h = { (_Float16)v.x, (_Float16)v.y, (_Float16)v.z, (_Float16)v.w };
        *(f16x4*)(plane + hidx) = h;

        float s = v.x * v.x + v.y * v.y + v.z * v.z + v.w * v.w;
        #pragma unroll
        for (int off = 32; off; off >>= 1) s += __shfl_down(s, off, 64);
        if (l == 0) { sq[row] = s; my_sumsq += s; }
    }
    if (l == 0) smq[w] = my_sumsq;
    *(float4*)&cls[w][l * 4] = colacc;
    __syncthreads();

    colpart[blockIdx.x * 256 + t] = cls[0][t] + cls[1][t] + cls[2][t] + cls[3][t];
    if (t == 0) ssqpart[blockIdx.x] = smq[0] + smq[1] + smq[2] + smq[3];
    // whole wave in ballot; per-lane predicate guards range + OOB
    if (w == 1) {
        unsigned long long m1 = __ballot(l < 16 && (int)sub[base + l] == 0);
        if (l == 0) n0part[blockIdx.x] = (unsigned int)__popcll(m1);
    }
}

// ---------------------------------------------------------------- K2: reduce partials -> scalars; init k3 state
__global__ __launch_bounds__(1024) void k2_scalars(const float* __restrict__ colpart,
                                                   const float* __restrict__ ssqpart,
                                                   const unsigned int* __restrict__ n0part,
                                                   Scalars* sc) {
    __shared__ float cp[4][256];
    __shared__ float r1[16], r2[16], r3[16];
    const int t = threadIdx.x;
    const int l = t & 63;
    const int w = t >> 6;
    const int col = t & 255;
    const int seg = t >> 8;

    float cs = 0.f;
    #pragma unroll 8
    for (int b = seg * 128; b < (seg + 1) * 128; ++b) cs += colpart[b * 256 + col];
    cp[seg][col] = cs;
    const float sv = (t < 512) ? ssqpart[t] : 0.f;
    const float nv = (t < 512) ? (float)n0part[t] : 0.f;
    __syncthreads();

    float a1 = 0.f;
    if (t < 256) {
        const float tot = cp[0][t] + cp[1][t] + cp[2][t] + cp[3][t];
        a1 = tot * tot;
    }
    float v1 = a1, v2 = sv, v3 = nv;
    #pragma unroll
    for (int off = 32; off; off >>= 1) {
        v1 += __shfl_down(v1, off, 64);
        v2 += __shfl_down(v2, off, 64);
        v3 += __shfl_down(v3, off, 64);
    }
    if (l == 0) { r1[w] = v1; r2[w] = v2; r3[w] = v3; }
    __syncthreads();
    if (t == 0) {
        double s1 = 0.0, s2 = 0.0, s3 = 0.0;
        #pragma unroll
        for (int i = 0; i < 16; ++i) { s1 += r1[i]; s2 += r2[i]; s3 += r3[i]; }
        const double n = (double)N_ROWS;
        const double sumL2 = 2.0 * n * s2 - 2.0 * s1;
        const double bw = sumL2 / (n * n - n) / 4.0;   // / KERNEL_MUL^(KERNEL_NUM/2)
        sc->c2 = (float)(-1.4426950408889634 / (16.0 * bw));
        const double n0 = s3;
        const double n1 = n - n0;
        sc->w0 = (float)( 1.0 / n0);
        sc->w1 = (float)(-1.0 / n1);
        sc->ctr = 0u;            // k3 chunk queue
        sc->t3  = 0u;            // k3 completion ticket
    }
}

// ---------------------------------------------------------------- K3: chunked ticket-queue MFMA Gram
// 512 blocks, dynamic queue of 544 chunks. Chunk = row-panel bi x up to 4 tiles.
// A (128x256 fp16 = 64KB) staged ONCE per chunk via global_load_lds.
// B: 16 fragments per tile loaded by REAL asm global_load_dwordx4 -> one
// s_waitcnt vmcnt(0) per tile = one latency window (vs 16 serial in r6-r8).
// Next tile's B + scalars prefetched during the current tile's epilogue.
__global__ __launch_bounds__(256, 2) void k3_mmd(const unsigned short* __restrict__ plane,
                                                 const long long* __restrict__ sub,
                                                 const float* __restrict__ sq,
                                                 Scalars* sc,
                                                 double* __restrict__ partial,
                                                 float* __restrict__ out) {
    __shared__ char ldsA[65536];
    __shared__ float2 sqwI[128];
    __shared__ double dd[4];
    __shared__ unsigned int qb;

    const int t  = threadIdx.x;
    const int l  = t & 63;
    const int w  = t >> 6;        // wave = J-column group (1x4 wave grid)
    const int lh = l >> 5;
    const int ln = l & 31;

    const float c2 = sc->c2, w0 = sc->w0, w1 = sc->w1;

    double dsum = 0.0;
    f16x8 b[16];

    for (;;) {
        __syncthreads();                       // protect A/sqwI from prev chunk readers
        if (t == 0) qb = atomicAdd(&sc->ctr, 1u);
        __syncthreads();
        const unsigned q0 = qb;
        if (q0 >= NCHUNK) break;               // uniform exit
        int q = (int)q0, bi = 0;
        for (;;) { const int nc = (NTILE - bi + 3) >> 2; if (q < nc) break; q -= nc; ++bi; }
        int bj = bi + q * 4;
        const int ntr = NTILE - bi - q * 4;
        const int nt  = ntr < 4 ? ntr : 4;

        // ---- stage A full-K: wave w stages rowblk bi*4+w (16 x 1KB regions)
        #pragma unroll
        for (int i = 0; i < 16; ++i) {
            const unsigned short* g = plane + (((size_t)(bi * 4 + w) * 16 + i) << 9) + (l << 3);
            char* lp = ldsA + ((w * 16 + i) << 10);
            __builtin_amdgcn_global_load_lds(
                (const __attribute__((address_space(1))) unsigned int*)(const void*)g,
                (__attribute__((address_space(3))) unsigned int*)(void*)lp, 16, 0, 0);
        }
        // ---- stage I-side (sq, weight) once per chunk
        if (t < 128) {
            const int I = bi * 128 + t;
            sqwI[t] = make_float2(sq[I], ((int)sub[I] == 0) ? w0 : w1);
        }
        // ---- first tile's B via asm loads (ride the same drain window)
        {
            const unsigned short* p0 = plane + (((size_t)(bj * 4 + w) * 16) << 9) + (l << 3);
            const unsigned short* p1 = p0 + 2048;   // +4096 B
            const unsigned short* p2 = p0 + 4096;
            const unsigned short* p3 = p0 + 6144;
            BL(b[0], p0,"0"); BL(b[1], p0,"1024"); BL(b[2], p0,"2048"); BL(b[3], p0,"3072");
            BL(b[4], p1,"0"); BL(b[5], p1,"1024"); BL(b[6], p1,"2048"); BL(b[7], p1,"3072");
            BL(b[8], p2,"0"); BL(b[9], p2,"1024"); BL(b[10],p2,"2048"); BL(b[11],p2,"3072");
            BL(b[12],p3,"0"); BL(b[13],p3,"1024"); BL(b[14],p3,"2048"); BL(b[15],p3,"3072");
        }
        const int J0 = bj * 128 + w * 32 + ln;
        float sJ  = sq[J0];
        float wJv = ((int)sub[J0] == 0) ? w0 : w1;
        __syncthreads();                       // ONE drain: A-DMA + B + sqwI

        for (int tt = 0; tt < nt; ++tt, ++bj) {
            const bool dg = (bj == bi);
            asm volatile("s_waitcnt vmcnt(0)" ::: "memory");  // B (+prefetch) landed
            __builtin_amdgcn_sched_barrier(0);                // rule #18: no hoisting

            f32x16 acc[4] = {};
            #pragma unroll
            for (int ks = 0; ks < 16; ++ks) {
                #pragma unroll
                for (int m = 0; m < 4; ++m) {
                    const f16x8 a = *(const f16x8*)(ldsA + ((m * 16 + ks) << 10) + (l << 4));
                    acc[m] = __builtin_amdgcn_mfma_f32_32x32x16_f16(a, b[ks], acc[m], 0, 0, 0);
                }
            }

            // ---- prefetch next tile's B + scalars (fly under the epilogue)
            float sJn = 0.f, wJn = 0.f;
            if (tt + 1 < nt) {
                const unsigned short* p0 = plane + (((size_t)((bj + 1) * 4 + w) * 16) << 9) + (l << 3);
                const unsigned short* p1 = p0 + 2048;
                const unsigned short* p2 = p0 + 4096;
                const unsigned short* p3 = p0 + 6144;
                BL(b[0], p0,"0"); BL(b[1], p0,"1024"); BL(b[2], p0,"2048"); BL(b[3], p0,"3072");
                BL(b[4], p1,"0"); BL(b[5], p1,"1024"); BL(b[6], p1,"2048"); BL(b[7], p1,"3072");
                BL(b[8], p2,"0"); BL(b[9], p2,"1024"); BL(b[10],p2,"2048"); BL(b[11],p2,"3072");
                BL(b[12],p3,"0"); BL(b[13],p3,"1024"); BL(b[14],p3,"2048"); BL(b[15],p3,"3072");
                const int Jn = (bj + 1) * 128 + w * 32 + ln;
                sJn = sq[Jn];
                wJn = ((int)sub[Jn] == 0) ? w0 : w1;
            }

            // ---- epilogue: L2 -> multi-scale kernel -> weighted partial sum
            float part = 0.f;
            #pragma unroll
            for (int m = 0; m < 4; ++m) {
                #pragma unroll
                for (int r = 0; r < 16; ++r) {
                    // C/D layout: col = lane&31, row = (r&3) + 8*(r>>2) + 4*(lane>>5)
                    const int Il = m * 32 + (r & 3) + ((r >> 2) << 3) + (lh << 2);
                    const float2 pi = sqwI[Il];
                    float l2 = fmaxf(pi.x + sJ - 2.f * acc[m][r], 0.f);
                    const float e  = __builtin_amdgcn_exp2f(l2 * c2);
                    const float e2 = e * e, e4 = e2 * e2, e8 = e4 * e4;
                    const float K  = ((e + e2) + (e4 + e8)) + e8 * e8;
                    float w2 = pi.y * wJv;
                    if (dg) {
                        const int Jl = w * 32 + ln;
                        w2 *= (Il < Jl) ? 2.f : ((Il == Jl) ? 1.f : 0.f);
                    }
                    part = fmaf(K, w2, part);
                }
            }
            dsum += (double)part * (dg ? 1.0 : 2.0);
            sJ = sJn; wJv = wJn;
        }
    }

    // ---- block reduce -> partial[bid]; last block reduces all -> out
    #pragma unroll
    for (int off = 32; off; off >>= 1) dsum += __shfl_down(dsum, off, 64);
    __syncthreads();
    if (l == 0) dd[w] = dsum;
    __syncthreads();
    if (t == 0) {
        partial[blockIdx.x] = dd[0] + dd[1] + dd[2] + dd[3];
        __threadfence();       // release: partial visible before ticket bump
        qb = (atomicAdd(&sc->t3, 1u) == K3B - 1) ? 1u : 0u;
    }
    __syncthreads();
    if (qb) {                  // block-uniform last-block flag
        __threadfence();       // acquire: see all producers' partials
        double v = partial[t] + partial[t + 256];
        #pragma unroll
        for (int off = 32; off; off >>= 1) v += __shfl_down(v, off, 64);
        if (l == 0) dd[w] = v;
        __syncthreads();
        if (t == 0) out[0] = (float)(dd[0] + dd[1] + dd[2] + dd[3]);
    }
}

extern "C" void kernel_launch(void* const* d_in, const int* in_sizes, int n_in,
                              void* d_out, int out_size, void* d_ws, size_t ws_size,
                              hipStream_t stream) {
    const long long* sub = (const long long*)d_in[0];   // subggroup int64 (N,1)
    const float*     x   = (const float*)d_in[1];       // outputs fp32 (N,256)
    float* out = (float*)d_out;

    char* ws = (char*)d_ws;
    unsigned short* plane   = (unsigned short*)(ws + WS_PLANE);
    float*          sq      = (float*)(ws + WS_SQ);
    float*          colpart = (float*)(ws + WS_COLP);
    float*          ssqpart = (float*)(ws + WS_SSQ);
    unsigned int*   n0part  = (unsigned int*)(ws + WS_N0);
    Scalars*        sc      = (Scalars*)(ws + WS_SC);
    double*         partial = (double*)(ws + WS_PART);

    k1_rows<<<K1B, 256, 0, stream>>>(x, sub, sq, colpart, ssqpart, n0part, plane);
    k2_scalars<<<1, 1024, 0, stream>>>(colpart, ssqpart, n0part, sc);
    k3_mmd<<<K3B, 256, 0, stream>>>(plane, sub, sq, sc, partial, out);
}